// Round 1
// 167.936 us; speedup vs baseline: 1.0658x; 1.0658x over previous
//
#include <hip/hip_runtime.h>

// Problem constants (fixed by setup_inputs): mask [64,480,864] fp32.
constexpr int B = 64;
constexpr int H = 480;
constexpr int W = 864;
constexpr float PROB_THRESHOLD = 0.5f;

constexpr int BPS = 16;                        // blocks per sample (power of 2)
constexpr int ROWS_PER_BLK = H / BPS;          // 30
constexpr int W4 = W / 4;                      // 216 float4 per row
constexpr int N4_PER_BLK = ROWS_PER_BLK * W4;  // 6480 float4 per block
constexpr int NBLK = B * BPS;                  // 1024 blocks = 4/CU x 256 CUs
constexpr int NPAIRS = ROWS_PER_BLK / 2;       // 15 outside-in row pairs

using f32x4 = __attribute__((ext_vector_type(4))) float;
using u64 = unsigned long long;

// Packed partial: minr:9 @0 | maxr+1:9 @9 | minc:10 @18 | maxc+1:10 @28 |
// cnt(sat 4095):12 @38 | zeros @50..55 | marker 0xFF @56.
// Workspace poison is 0xAAAA... (top byte 0xAA != 0xFF) -> no init pass.
constexpr u64 MARKER = 0xFFull << 56;

__device__ inline u64 pack_partial(int minr, int maxr, int minc, int maxc,
                                   int cnt) {
  u64 v = (u64)(unsigned)minr | ((u64)(unsigned)(maxr + 1) << 9) |
          ((u64)(unsigned)minc << 18) | ((u64)(unsigned)(maxc + 1) << 28) |
          ((u64)(unsigned)min(cnt, 4095) << 38) | MARKER;
  return v;
}

// ---------------------------------------------------------------------------
// Phase 1 is now an EARLY-TERMINATING outside-in row-pair scan:
//   A block's partial (minr,maxr,minc,maxc,cnt) is provably FINAL once it has
//   OBSERVED hits at rows row0 and row0+29 (its slab extremes) and columns 0
//   and W-1 (the global extremes), with cnt >= thr. Every unread pixel is then
//   dominated: it cannot lower a min that is already at its bound, raise a max
//   at its bound, and cnt only needs exactness below thr (above it the
//   full-frame decision is already fixed; we publish saturated 4095).
//   Scanning row pairs (s, 29-s) from both ends reaches this state after
//   E[~1.6] pairs on p=0.5 data -> ~6x less read traffic. Worst case (no
//   early stop) scans everything and takes the exact-reduce fallback, so the
//   kernel stays correct for arbitrary inputs.
// Phase 2 (unchanged, proven): fenceless per-sample software barrier via one
//   packed relaxed agent-scope atomic word per block, then NT float4 stores.
// ---------------------------------------------------------------------------
__global__ __launch_bounds__(256, 4) void fused_kernel(
    const float* __restrict__ mask, const int* __restrict__ n_pts_threshold,
    const int* __restrict__ n_bbox_loose, float* __restrict__ out,
    float* __restrict__ bbox_out, u64* __restrict__ part) {
  const int b    = blockIdx.x >> 4;  // / BPS
  const int blk  = blockIdx.x & 15;  // % BPS
  const int row0 = blk * ROWS_PER_BLK;
  const f32x4* __restrict__ m4 =
      (const f32x4*)(mask + ((size_t)b * H + row0) * (size_t)W);

  const int thr = n_pts_threshold[0];
  const int tid = threadIdx.x;
  const int wave = tid >> 6;
  const int lane = tid & 63;

  // Per-thread fixed geometry: pair s covers rows t=s and bb=29-s (relative).
  // Elem A: tid<216 -> (row t, col4 tid); tid>=216 -> (row bb, col4 tid-216).
  // Elem B (tid<176): (row bb, col4 tid+40). Row bb thus covered 0..215.
  const bool aTop = tid < W4;
  const int aC4   = aTop ? tid : tid - W4;
  const bool hasB = tid < (2 * W4 - 256);   // 176
  const int bC4   = tid + (256 - W4);       // tid + 40
  const int aC = aC4 * 4, bC = bC4 * 4;

  int minr = H, maxr = -1, minc = W, maxc = -1, cnt = 0;

  auto proc = [&](f32x4 v, int row, int c) {
    bool h0 = v.x > PROB_THRESHOLD;
    bool h1 = v.y > PROB_THRESHOLD;
    bool h2 = v.z > PROB_THRESHOLD;
    bool h3 = v.w > PROB_THRESHOLD;
    int m = (h0 ? 1 : 0) | (h1 ? 2 : 0) | (h2 ? 4 : 0) | (h3 ? 8 : 0);
    if (m) {
      minr = min(minr, row);
      maxr = max(maxr, row);
      minc = min(minc, c + (__ffs(m) - 1));
      maxc = max(maxc, c + (31 - __clz(m)));
      cnt += __popc(m);
    }
  };

  auto loadA = [&](int s) {
    int rr = aTop ? s : (ROWS_PER_BLK - 1 - s);
    return __builtin_nontemporal_load(&m4[rr * W4 + aC4]);
  };
  auto loadB = [&](int s) {
    return __builtin_nontemporal_load(&m4[(ROWS_PER_BLK - 1 - s) * W4 + bC4]);
  };

  __shared__ int rflags[4];  // per-wave OR of observed-extreme flags
  __shared__ int rcnt[4];    // per-wave hit count
  __shared__ int s5[4][5];   // fallback exact cross-wave reduce
  __shared__ u64 packed[BPS];

  bool stopped = false;
  f32x4 pa = loadA(0);
  f32x4 pb{};
  if (hasB) pb = loadB(0);

  for (int s = 0; s < NPAIRS; ++s) {
    f32x4 ca = pa, cb = pb;
    const int sn = (s + 1 < NPAIRS) ? s + 1 : s;  // clamped prefetch
    pa = loadA(sn);
    if (hasB) pb = loadB(sn);

    const int rt = row0 + s;
    const int rb = row0 + ROWS_PER_BLK - 1 - s;
    proc(ca, aTop ? rt : rb, aC);
    if (hasB) proc(cb, rb, bC);

    // Cheap block-wide stop check: 4x any-ballot + wave count-sum + LDS fold.
    int wc = cnt;
    for (int off = 1; off < 64; off <<= 1) wc += __shfl_xor(wc, off);
    int fl = (__any(minr == row0) ? 1 : 0) |
             (__any(maxr == row0 + ROWS_PER_BLK - 1) ? 2 : 0) |
             (__any(minc == 0) ? 4 : 0) |
             (__any(maxc == W - 1) ? 8 : 0);
    if (lane == 0) { rflags[wave] = fl; rcnt[wave] = wc; }
    __syncthreads();
    const int bfl  = rflags[0] | rflags[1] | rflags[2] | rflags[3];
    const int bcnt = rcnt[0] + rcnt[1] + rcnt[2] + rcnt[3];
    const bool stop = (bfl == 15) && (bcnt >= thr);
    __syncthreads();  // protect rflags/rcnt reuse on next pair
    if (stop) { stopped = true; break; }
  }

  u64* __restrict__ P = part + (size_t)b * BPS;  // this sample's slots
  if (stopped) {
    // Extremes were OBSERVED (real hits) -> partial is exact for bbox fields;
    // cnt>=thr -> saturated publish is decision-equivalent.
    if (tid == 0)
      __hip_atomic_store(
          &P[blk],
          pack_partial(row0, row0 + ROWS_PER_BLK - 1, 0, W - 1, 4095),
          __ATOMIC_RELAXED, __HIP_MEMORY_SCOPE_AGENT);
  } else {
    // Fallback: exact full reduce (wave shuffle + LDS), as before.
    for (int off = 32; off > 0; off >>= 1) {
      minr = min(minr, __shfl_down(minr, off));
      maxr = max(maxr, __shfl_down(maxr, off));
      minc = min(minc, __shfl_down(minc, off));
      maxc = max(maxc, __shfl_down(maxc, off));
      cnt += __shfl_down(cnt, off);
    }
    if (lane == 0) {
      s5[wave][0] = minr; s5[wave][1] = maxr;
      s5[wave][2] = minc; s5[wave][3] = maxc;
      s5[wave][4] = cnt;
    }
    __syncthreads();
    if (tid == 0) {
      for (int wv = 1; wv < 4; ++wv) {
        minr = min(minr, s5[wv][0]);
        maxr = max(maxr, s5[wv][1]);
        minc = min(minc, s5[wv][2]);
        maxc = max(maxc, s5[wv][3]);
        cnt += s5[wv][4];
      }
      __hip_atomic_store(&P[blk], pack_partial(minr, maxr, minc, maxc, cnt),
                         __ATOMIC_RELAXED, __HIP_MEMORY_SCOPE_AGENT);
    }
  }

  // ---- Per-sample barrier: fenceless relaxed polls ----
  if (tid < BPS) {
    u64 v;
    while (((v = __hip_atomic_load(&P[tid], __ATOMIC_RELAXED,
                                   __HIP_MEMORY_SCOPE_AGENT)) >> 56) != 0xFF)
      __builtin_amdgcn_s_sleep(2);
    packed[tid] = v;
  }
  __syncthreads();

  // ---- Phase 2: fold packed partials (LDS broadcast) + fill ----
  minr = H; maxr = -1; minc = W; maxc = -1; cnt = 0;
#pragma unroll
  for (int k = 0; k < BPS; ++k) {
    u64 v = packed[k];
    minr = min(minr, (int)(v & 511));
    maxr = max(maxr, (int)((v >> 9) & 511) - 1);
    minc = min(minc, (int)((v >> 18) & 1023));
    maxc = max(maxc, (int)((v >> 28) & 1023) - 1);
    cnt += (int)((v >> 38) & 4095);  // saturated at 4095 >= thr=10: OK
  }
  const int loose = n_bbox_loose[0];
  int y0, y1, x0, x1;
  if (cnt < thr) {
    y0 = 0; y1 = H - 1; x0 = 0; x1 = W - 1;
  } else {
    y0 = min(max(minr - loose, 0), H - 1);
    y1 = min(max(maxr + loose, 0), H - 1);
    x0 = min(max(minc - loose, 0), W - 1);
    x1 = min(max(maxc + loose, 0), W - 1);
  }
  if (blk == 0 && tid == 0) {
    bbox_out[b * 4 + 0] = (float)y0;
    bbox_out[b * 4 + 1] = (float)y1;
    bbox_out[b * 4 + 2] = (float)x0;
    bbox_out[b * 4 + 3] = (float)x1;
  }

  f32x4* obase = (f32x4*)(out + ((size_t)b * H + row0) * (size_t)W);

  auto val4 = [&](int i2) {
    int r = i2 / W4;
    int c = (i2 - r * W4) * 4;
    int rr = row0 + r;
    bool inr = (rr >= y0) & (rr <= y1);
    f32x4 v;
    v.x = (inr & (c + 0 >= x0) & (c + 0 <= x1)) ? 1.0f : 0.0f;
    v.y = (inr & (c + 1 >= x0) & (c + 1 <= x1)) ? 1.0f : 0.0f;
    v.z = (inr & (c + 2 >= x0) & (c + 2 <= x1)) ? 1.0f : 0.0f;
    v.w = (inr & (c + 3 >= x0) & (c + 3 <= x1)) ? 1.0f : 0.0f;
    return v;
  };

  int i = tid;
  for (int it = 0; it < 6; ++it, i += 1024) {
    __builtin_nontemporal_store(val4(i),       &obase[i]);
    __builtin_nontemporal_store(val4(i + 256), &obase[i + 256]);
    __builtin_nontemporal_store(val4(i + 512), &obase[i + 512]);
    __builtin_nontemporal_store(val4(i + 768), &obase[i + 768]);
  }
  __builtin_nontemporal_store(val4(i), &obase[i]);
  i += 256;
  if (i < N4_PER_BLK) __builtin_nontemporal_store(val4(i), &obase[i]);
}

extern "C" void kernel_launch(void* const* d_in, const int* in_sizes, int n_in,
                              void* d_out, int out_size, void* d_ws,
                              size_t ws_size, hipStream_t stream) {
  const float* mask = (const float*)d_in[0];
  const int* n_pts_threshold = (const int*)d_in[1];
  const int* n_bbox_loose = (const int*)d_in[2];

  float* out = (float*)d_out;
  float* bbox_out = out + (size_t)B * H * W;  // tuple outputs concatenated
  u64* part = (u64*)d_ws;                     // NBLK * 8 B

  fused_kernel<<<NBLK, 256, 0, stream>>>(mask, n_pts_threshold, n_bbox_loose,
                                         out, bbox_out, part);
}

// Round 2
// 167.104 us; speedup vs baseline: 1.0711x; 1.0050x over previous
//
#include <hip/hip_runtime.h>

// Problem constants (fixed by setup_inputs): mask [64,480,864] fp32.
constexpr int B = 64;
constexpr int H = 480;
constexpr int W = 864;
constexpr float PROB_THRESHOLD = 0.5f;

constexpr int BPS = 16;                        // blocks per sample (power of 2)
constexpr int ROWS_PER_BLK = H / BPS;          // 30
constexpr int W4 = W / 4;                      // 216 float4 per row
constexpr int N4_PER_BLK = ROWS_PER_BLK * W4;  // 6480 float4 per block
constexpr int NBLK = B * BPS;                  // 1024 blocks = 4/CU x 256 CUs
constexpr int NPAIRS = ROWS_PER_BLK / 2;       // 15 outside-in row pairs

using f32x4 = __attribute__((ext_vector_type(4))) float;
using u64 = unsigned long long;

// Packed partial: minr:9 @0 | maxr+1:9 @9 | minc:10 @18 | maxc+1:10 @28 |
// cnt(sat 4095):12 @38 | zeros @50..55 | marker 0xFF @56.
// Workspace poison is 0xAAAA... (top byte 0xAA != 0xFF) -> no init pass.
constexpr u64 MARKER = 0xFFull << 56;

__device__ inline u64 pack_partial(int minr, int maxr, int minc, int maxc,
                                   int cnt) {
  u64 v = (u64)(unsigned)minr | ((u64)(unsigned)(maxr + 1) << 9) |
          ((u64)(unsigned)minc << 18) | ((u64)(unsigned)(maxc + 1) << 28) |
          ((u64)(unsigned)min(cnt, 4095) << 38) | MARKER;
  return v;
}

// ---------------------------------------------------------------------------
// Phase 1: EARLY-TERMINATING outside-in row-pair scan (see R1 proof: partial
//   is final once hits observed at slab-extreme rows + global column extremes
//   with cnt >= thr). R2 changes:
//   (a) pair 0 is processed with NO prefetch -> blocks that stop at pair 0
//       (p~0.56 on this data) read exactly 2 rows, not 4.
//   (b) stop-check uses parity-indexed vote buffers -> ONE __syncthreads per
//       pair (reads of slot s&1 are separated from the next write to that
//       slot by the barrier at pair s+1).
// Barrier: fenceless per-sample relaxed agent-scope publish/poll (proven in
//   earlier session; release fences collapsed BW to 1.9 TB/s).
// Phase 2: row-structured NT store: thread t<216 owns column-group t for all
//   30 rows; column predicate vector computed ONCE, per row one cndmask+store.
// ---------------------------------------------------------------------------
__global__ __launch_bounds__(256, 4) void fused_kernel(
    const float* __restrict__ mask, const int* __restrict__ n_pts_threshold,
    const int* __restrict__ n_bbox_loose, float* __restrict__ out,
    float* __restrict__ bbox_out, u64* __restrict__ part) {
  const int b    = blockIdx.x >> 4;  // / BPS
  const int blk  = blockIdx.x & 15;  // % BPS
  const int row0 = blk * ROWS_PER_BLK;
  const f32x4* __restrict__ m4 =
      (const f32x4*)(mask + ((size_t)b * H + row0) * (size_t)W);

  const int thr = n_pts_threshold[0];
  const int tid = threadIdx.x;
  const int wave = tid >> 6;
  const int lane = tid & 63;

  // Per-thread fixed geometry: pair s covers rows t=s and bb=29-s (relative).
  // Elem A: tid<216 -> (row t, col4 tid); tid>=216 -> (row bb, col4 tid-216).
  // Elem B (tid<176): (row bb, col4 tid+40). Row bb thus covered 0..215.
  const bool aTop = tid < W4;
  const int aC4   = aTop ? tid : tid - W4;
  const bool hasB = tid < (2 * W4 - 256);   // 176
  const int bC4   = tid + (256 - W4);       // tid + 40
  const int aC = aC4 * 4, bC = bC4 * 4;

  int minr = H, maxr = -1, minc = W, maxc = -1, cnt = 0;

  auto proc = [&](f32x4 v, int row, int c) {
    bool h0 = v.x > PROB_THRESHOLD;
    bool h1 = v.y > PROB_THRESHOLD;
    bool h2 = v.z > PROB_THRESHOLD;
    bool h3 = v.w > PROB_THRESHOLD;
    int m = (h0 ? 1 : 0) | (h1 ? 2 : 0) | (h2 ? 4 : 0) | (h3 ? 8 : 0);
    if (m) {
      minr = min(minr, row);
      maxr = max(maxr, row);
      minc = min(minc, c + (__ffs(m) - 1));
      maxc = max(maxc, c + (31 - __clz(m)));
      cnt += __popc(m);
    }
  };

  auto loadA = [&](int s) {
    int rr = aTop ? s : (ROWS_PER_BLK - 1 - s);
    return __builtin_nontemporal_load(&m4[rr * W4 + aC4]);
  };
  auto loadB = [&](int s) {
    return __builtin_nontemporal_load(&m4[(ROWS_PER_BLK - 1 - s) * W4 + bC4]);
  };

  __shared__ int vfl[2][4];   // parity-indexed per-wave vote: extreme flags
  __shared__ int vcn[2][4];   // parity-indexed per-wave vote: hit count
  __shared__ int s5[4][5];    // fallback exact cross-wave reduce
  __shared__ u64 packed[BPS];

  // Block-wide stop check, ONE barrier per pair via parity slots.
  auto stopCheck = [&](int s) -> bool {
    int wc = cnt;
    for (int off = 1; off < 64; off <<= 1) wc += __shfl_xor(wc, off);
    int fl = (__any(minr == row0) ? 1 : 0) |
             (__any(maxr == row0 + ROWS_PER_BLK - 1) ? 2 : 0) |
             (__any(minc == 0) ? 4 : 0) |
             (__any(maxc == W - 1) ? 8 : 0);
    const int p = s & 1;
    if (lane == 0) { vfl[p][wave] = fl; vcn[p][wave] = wc; }
    __syncthreads();
    const int bfl  = vfl[p][0] | vfl[p][1] | vfl[p][2] | vfl[p][3];
    const int bcnt = vcn[p][0] + vcn[p][1] + vcn[p][2] + vcn[p][3];
    return (bfl == 15) & (bcnt >= thr);
  };

  bool stopped;
  {  // pair 0: no prefetch -> stopping blocks read exactly 2 rows.
    f32x4 ca = loadA(0), cb{};
    if (hasB) cb = loadB(0);
    proc(ca, aTop ? row0 : row0 + ROWS_PER_BLK - 1, aC);
    if (hasB) proc(cb, row0 + ROWS_PER_BLK - 1, bC);
    stopped = stopCheck(0);
  }
  if (!stopped) {
    f32x4 pa = loadA(1), pb{};
    if (hasB) pb = loadB(1);
    for (int s = 1; s < NPAIRS; ++s) {
      f32x4 ca = pa, cb = pb;
      const int sn = (s + 1 < NPAIRS) ? s + 1 : s;  // clamped prefetch
      pa = loadA(sn);
      if (hasB) pb = loadB(sn);
      const int rt = row0 + s;
      const int rb = row0 + ROWS_PER_BLK - 1 - s;
      proc(ca, aTop ? rt : rb, aC);
      if (hasB) proc(cb, rb, bC);
      if ((stopped = stopCheck(s))) break;
    }
  }

  u64* __restrict__ P = part + (size_t)b * BPS;  // this sample's slots
  if (stopped) {
    // Extremes were OBSERVED (real hits) -> partial exact for bbox fields;
    // cnt>=thr -> saturated publish is decision-equivalent.
    if (tid == 0)
      __hip_atomic_store(
          &P[blk],
          pack_partial(row0, row0 + ROWS_PER_BLK - 1, 0, W - 1, 4095),
          __ATOMIC_RELAXED, __HIP_MEMORY_SCOPE_AGENT);
  } else {
    // Fallback: exact full reduce (wave shuffle + LDS), as before.
    for (int off = 32; off > 0; off >>= 1) {
      minr = min(minr, __shfl_down(minr, off));
      maxr = max(maxr, __shfl_down(maxr, off));
      minc = min(minc, __shfl_down(minc, off));
      maxc = max(maxc, __shfl_down(maxc, off));
      cnt += __shfl_down(cnt, off);
    }
    if (lane == 0) {
      s5[wave][0] = minr; s5[wave][1] = maxr;
      s5[wave][2] = minc; s5[wave][3] = maxc;
      s5[wave][4] = cnt;
    }
    __syncthreads();
    if (tid == 0) {
      for (int wv = 1; wv < 4; ++wv) {
        minr = min(minr, s5[wv][0]);
        maxr = max(maxr, s5[wv][1]);
        minc = min(minc, s5[wv][2]);
        maxc = max(maxc, s5[wv][3]);
        cnt += s5[wv][4];
      }
      __hip_atomic_store(&P[blk], pack_partial(minr, maxr, minc, maxc, cnt),
                         __ATOMIC_RELAXED, __HIP_MEMORY_SCOPE_AGENT);
    }
  }

  // ---- Per-sample barrier: fenceless relaxed polls ----
  if (tid < BPS) {
    u64 v;
    while (((v = __hip_atomic_load(&P[tid], __ATOMIC_RELAXED,
                                   __HIP_MEMORY_SCOPE_AGENT)) >> 56) != 0xFF)
      __builtin_amdgcn_s_sleep(2);
    packed[tid] = v;
  }
  __syncthreads();

  // ---- Phase 2: fold packed partials (LDS broadcast) + fill ----
  minr = H; maxr = -1; minc = W; maxc = -1; cnt = 0;
#pragma unroll
  for (int k = 0; k < BPS; ++k) {
    u64 v = packed[k];
    minr = min(minr, (int)(v & 511));
    maxr = max(maxr, (int)((v >> 9) & 511) - 1);
    minc = min(minc, (int)((v >> 18) & 1023));
    maxc = max(maxc, (int)((v >> 28) & 1023) - 1);
    cnt += (int)((v >> 38) & 4095);  // saturated at 4095 >= thr=10: OK
  }
  const int loose = n_bbox_loose[0];
  int y0, y1, x0, x1;
  if (cnt < thr) {
    y0 = 0; y1 = H - 1; x0 = 0; x1 = W - 1;
  } else {
    y0 = min(max(minr - loose, 0), H - 1);
    y1 = min(max(maxr + loose, 0), H - 1);
    x0 = min(max(minc - loose, 0), W - 1);
    x1 = min(max(maxc + loose, 0), W - 1);
  }
  if (blk == 0 && tid == 0) {
    bbox_out[b * 4 + 0] = (float)y0;
    bbox_out[b * 4 + 1] = (float)y1;
    bbox_out[b * 4 + 2] = (float)x0;
    bbox_out[b * 4 + 3] = (float)x1;
  }

  // Row-structured write: thread t<216 owns column-group t for all 30 rows.
  // Column predicate computed once; per row: one vector select + NT store.
  if (tid < W4) {
    const int c = tid * 4;
    f32x4 colv, zero;
    colv.x = ((c + 0 >= x0) & (c + 0 <= x1)) ? 1.0f : 0.0f;
    colv.y = ((c + 1 >= x0) & (c + 1 <= x1)) ? 1.0f : 0.0f;
    colv.z = ((c + 2 >= x0) & (c + 2 <= x1)) ? 1.0f : 0.0f;
    colv.w = ((c + 3 >= x0) & (c + 3 <= x1)) ? 1.0f : 0.0f;
    zero.x = 0.0f; zero.y = 0.0f; zero.z = 0.0f; zero.w = 0.0f;

    f32x4* p = (f32x4*)(out + ((size_t)b * H + row0) * (size_t)W) + tid;
    int rr = row0;
#pragma unroll
    for (int r = 0; r < ROWS_PER_BLK; ++r, ++rr, p += W4) {
      const bool inr = (rr >= y0) & (rr <= y1);
      __builtin_nontemporal_store(inr ? colv : zero, p);
    }
  }
}

extern "C" void kernel_launch(void* const* d_in, const int* in_sizes, int n_in,
                              void* d_out, int out_size, void* d_ws,
                              size_t ws_size, hipStream_t stream) {
  const float* mask = (const float*)d_in[0];
  const int* n_pts_threshold = (const int*)d_in[1];
  const int* n_bbox_loose = (const int*)d_in[2];

  float* out = (float*)d_out;
  float* bbox_out = out + (size_t)B * H * W;  // tuple outputs concatenated
  u64* part = (u64*)d_ws;                     // NBLK * 8 B

  fused_kernel<<<NBLK, 256, 0, stream>>>(mask, n_pts_threshold, n_bbox_loose,
                                         out, bbox_out, part);
}